// Round 9
// baseline (249.106 us; speedup 1.0000x reference)
//
#include <hip/hip_runtime.h>
#include <hip/hip_bf16.h>

#define BATCH 128
#define SGRID 32
#define NCELL 1024
#define NTOT  1025
#define FD    128
#define NACT  19
#define NEG_INF_F  (-3.4028234663852886e38f)  // jnp.finfo(float32).min
#define BF16_SAFE_F (3.3e38f)                 // < bf16 max finite (3.3895e38)
#define XSTR 136                              // LDS row stride (bf16); 272B keeps b128 align

typedef unsigned short ushort_t;
typedef unsigned int   uint_t;
typedef short   short8   __attribute__((ext_vector_type(8)));
typedef float   floatx16 __attribute__((ext_vector_type(16)));
typedef float   floatx2  __attribute__((ext_vector_type(2)));

__device__ __forceinline__ float elu_fast(float v) {   // bf16-accurate ELU
    return v > 0.f ? v : (__expf(v) - 1.f);
}
__device__ __forceinline__ float bf2f(ushort_t h) {
    union { uint_t u; float f; } v; v.u = ((uint_t)h) << 16; return v.f;
}
__device__ __forceinline__ ushort_t f2bf(float f) {   // round-to-nearest-even
    union { float f; uint_t u; } v; v.f = f;
    uint_t r = v.u + 0x7FFFu + ((v.u >> 16) & 1u);
    return (ushort_t)(r >> 16);
}
__device__ __forceinline__ uint_t pkbf(float a, float b) {  // v_cvt_pk_bf16_f32
    union { __hip_bfloat162 h; uint_t u; } v;
    v.h = __float22bfloat162_rn(make_float2(a, b));
    return v.u;
}
__device__ __forceinline__ floatx2 up2(uint_t u) {    // 2 bf16 -> float2
    union { uint_t x; float f; } lo, hi;
    lo.x = u << 16; hi.x = u & 0xFFFF0000u;
    floatx2 r; r.x = lo.f; r.y = hi.f; return r;
}
__device__ __forceinline__ void unpack2(uint_t u, float& a, float& b) {
    union { uint_t x; float f; } lo, hi;
    lo.x = u << 16; hi.x = u & 0xFFFF0000u;
    a = lo.f; b = hi.f;
}
__device__ __forceinline__ void unpack8(uint4 v, float* f) {
    unpack2(v.x, f[0], f[1]); unpack2(v.y, f[2], f[3]);
    unpack2(v.z, f[4], f[5]); unpack2(v.w, f[6], f[7]);
}
__device__ __forceinline__ void unpack4(uint2 v, float* f) {
    unpack2(v.x, f[0], f[1]); unpack2(v.y, f[2], f[3]);
}

// ---------------------------------------------------------------------------
// Pack GNN weights into MFMA B-fragment order for v_mfma_f32_32x32x16_bf16:
// B[k][n], lane layout n = lane&31, k = (lane>>5)*8 + j (j=0..7).
// group g = ((layer*2 + phase)*4 + ntile)*8*64 + ks*64 + lane; 8 bf16/group.
// ---------------------------------------------------------------------------
__global__ __launch_bounds__(256) void gnn_setup_frags(
    const ushort_t* __restrict__ Ws,   // 3 x 128 x 128, k-major
    const ushort_t* __restrict__ Wn,
    ushort_t* __restrict__ wfrag)
{
    const int g = blockIdx.x * 256 + threadIdx.x;   // 12288 groups
    if (g >= 3 * 2 * 4 * 8 * 64) return;
    const int lane = g & 63;
    const int ks   = (g >> 6) & 7;
    const int nt   = (g >> 9) & 3;
    const int p    = (g >> 11) & 1;
    const int l    = g >> 12;
    const ushort_t* W = (p ? Wn : Ws) + (size_t)l * FD * FD;
    const int k0  = ks * 16 + (lane >> 5) * 8;
    const int col = nt * 32 + (lane & 31);
    ushort_t v[8];
    #pragma unroll
    for (int j = 0; j < 8; ++j) v[j] = W[(size_t)(k0 + j) * FD + col];
    uint4 u;
    u.x = v[0] | ((uint_t)v[1] << 16); u.y = v[2] | ((uint_t)v[3] << 16);
    u.z = v[4] | ((uint_t)v[5] << 16); u.w = v[6] | ((uint_t)v[7] << 16);
    *(uint4*)(wfrag + (size_t)g * 8) = u;
}

// ---------------------------------------------------------------------------
// GNN layer, MFMA + XCD-swizzled + prefetched halo + meta-as-bias.
// y = elu(x@Ws + nb@Wn + (bs + mb) ) where nb = 4-neighbor sum and
// mb[b][col] = x_meta@Wn, precomputed by the PREVIOUS layer's meta block.
// Grid 2176: i&7 = XCD -> one batch image's 17 blocks share an XCD L2.
// LDS 34.8 KB (meta branch overlays tile storage) -> 4 blocks/CU.
// ---------------------------------------------------------------------------
__global__ __launch_bounds__(256, 4) void gnn_layer(
    const ushort_t* __restrict__ xprev,
    ushort_t* __restrict__ xnext,
    const ushort_t* __restrict__ wfrag_layer,
    const ushort_t* __restrict__ Ws,           // raw weights (meta block only)
    const ushort_t* __restrict__ Wn,
    const ushort_t* __restrict__ bs,
    const float* __restrict__ mb_in,           // this layer's meta-bias [B][FD]
    float* __restrict__ mb_out,                // next layer's meta-bias
    const ushort_t* __restrict__ Wn_next,      // raw Wn of next layer
    int meta_valid, int write_mb, int in_bstride)
{
    const int i = blockIdx.x;
    const int xcd = i & 7;
    const int j = i >> 3;
    const int b = xcd * 16 + j / 17;
    const int rb = j % 17;
    const int t = threadIdx.x;
    const ushort_t* xb = xprev + (size_t)b * in_bstride;
    ushort_t* yb = xnext + (size_t)b * (NTOT * FD);

    __shared__ alignas(16) ushort_t xt[64 * XSTR];   // x tile / meta scratch
    __shared__ alignas(16) ushort_t at[64 * XSTR];   // agg tile / meta scratch

    if (rb == 16) {
        // ---- meta node: reduce 1024 cells, 1x128 GEMM, then mb_out ----
        float* part = (float*)xt;              // 16 x 128 partials (8 KB)
        float* msum = (float*)at;              // 128
        float* xm   = (float*)at + FD;         // 128
        float* ym   = (float*)at + 2 * FD;     // 128 (this layer's meta out)
        const int kc = (t & 15) * 8;
        const int cg = t >> 4;
        float s[8];
        #pragma unroll
        for (int q = 0; q < 8; ++q) s[q] = 0.f;
        #pragma unroll 4
        for (int n = 0; n < 64; ++n) {
            const int cell = cg * 64 + n;
            float f[8]; unpack8(*(const uint4*)(xb + (size_t)cell * FD + kc), f);
            #pragma unroll
            for (int q = 0; q < 8; ++q) s[q] += f[q];
        }
        #pragma unroll
        for (int q = 0; q < 8; ++q) part[cg * FD + kc + q] = s[q];
        __syncthreads();
        if (t < FD) {
            float a = 0.f;
            #pragma unroll
            for (int gI = 0; gI < 16; ++gI) a += part[gI * FD + t];
            msum[t] = a;
            xm[t] = meta_valid ? bf2f(xb[(size_t)NCELL * FD + t]) : 0.f;
        }
        __syncthreads();
        if (t < FD) {
            float a = bf2f(bs[t]);
            #pragma unroll 4
            for (int kk = 0; kk < FD; ++kk)
                a += xm[kk] * bf2f(Ws[kk * FD + t]) + msum[kk] * bf2f(Wn[kk * FD + t]);
            const ushort_t yh = f2bf(elu_fast(a));
            yb[(size_t)NCELL * FD + t] = yh;
            ym[t] = bf2f(yh);                  // bf16-rounded, matches storage
        }
        __syncthreads();
        if (write_mb && t < FD) {
            float a = 0.f;
            #pragma unroll 4
            for (int kk = 0; kk < FD; ++kk)
                a += ym[kk] * bf2f(Wn_next[kk * FD + t]);
            mb_out[(size_t)b * FD + t] = a;
        }
        return;
    }

    // ---- row-pair block: grid rows r0, r0+1 (64 cells) ----
    const int r0 = rb * 2;

    // Phase 0: issue ALL global loads (main tile + halo rows) up front.
    const ushort_t* src = xb + (size_t)(r0 * SGRID) * FD;
    uint4 mainT[4], haloT[4];
    const uint4 zero4 = make_uint4(0u, 0u, 0u, 0u);
    #pragma unroll
    for (int jj = 0; jj < 4; ++jj) {
        const int e8 = (t + 256 * jj) * 8;     // 0..8184
        const int cc = e8 >> 7, k = e8 & 127;
        const int rr = cc >> 5, c = cc & 31;
        mainT[jj] = *(const uint4*)(src + e8);
        const int grow = (rr == 0) ? (r0 - 1) : (r0 + 2);
        haloT[jj] = (grow >= 0 && grow < SGRID)
            ? *(const uint4*)(xb + (size_t)(grow * SGRID + c) * FD + k) : zero4;
    }
    // Meta-bias for this block's output columns (tiny, L2-resident).
    const int w = t >> 6;        // wave id = n-tile
    const int l = t & 63;
    const int col = w * 32 + (l & 31);
    float mbv = 0.f;
    if (meta_valid) mbv = mb_in[(size_t)b * FD + col];

    #pragma unroll
    for (int jj = 0; jj < 4; ++jj) {
        const int e8 = (t + 256 * jj) * 8;
        const int cc = e8 >> 7, k = e8 & 127;
        *(uint4*)&xt[cc * XSTR + k] = mainT[jj];
    }
    __syncthreads();

    // Build neighbor-sum tile (bf16): laterals + inner vertical from LDS,
    // outer vertical from prefetched regs. Packed f32 adds (v_pk_add_f32).
    #pragma unroll
    for (int jj = 0; jj < 4; ++jj) {
        const int e8 = (t + 256 * jj) * 8;
        const int cc = e8 >> 7, k = e8 & 127;
        const int c = cc & 31;
        uint4 iv = *(const uint4*)&xt[(cc ^ 32) * XSTR + k];   // inner vertical
        floatx2 s0 = up2(iv.x), s1 = up2(iv.y), s2 = up2(iv.z), s3 = up2(iv.w);
        if (c > 0) {
            uint4 L = *(const uint4*)&xt[(cc - 1) * XSTR + k];
            s0 += up2(L.x); s1 += up2(L.y); s2 += up2(L.z); s3 += up2(L.w);
        }
        if (c < 31) {
            uint4 R = *(const uint4*)&xt[(cc + 1) * XSTR + k];
            s0 += up2(R.x); s1 += up2(R.y); s2 += up2(R.z); s3 += up2(R.w);
        }
        s0 += up2(haloT[jj].x); s1 += up2(haloT[jj].y);
        s2 += up2(haloT[jj].z); s3 += up2(haloT[jj].w);
        uint4 u;
        u.x = pkbf(s0.x, s0.y); u.y = pkbf(s1.x, s1.y);
        u.z = pkbf(s2.x, s2.y); u.w = pkbf(s3.x, s3.y);
        *(uint4*)&at[cc * XSTR + k] = u;
    }
    __syncthreads();

    // MFMA GEMM: M=64 (2 m-tiles) x N=128 (4 waves) x K=256.
    const int m0 = l & 31;
    const int koff = (l >> 5) * 8;

    floatx16 acc0, acc1;
    #pragma unroll
    for (int q = 0; q < 16; ++q) { acc0[q] = 0.f; acc1[q] = 0.f; }

    #pragma unroll
    for (int p = 0; p < 2; ++p) {
        const ushort_t* X = p ? at : xt;
        const ushort_t* WF = wfrag_layer + (size_t)((p * 4 + w) * 8) * 64 * 8;
        #pragma unroll
        for (int ks = 0; ks < 8; ++ks) {
            const short8 bfrag = *(const short8*)(WF + (size_t)(ks * 64 + l) * 8);
            const short8 av0 = *(const short8*)&X[m0 * XSTR + ks * 16 + koff];
            const short8 av1 = *(const short8*)&X[(m0 + 32) * XSTR + ks * 16 + koff];
            acc0 = __builtin_amdgcn_mfma_f32_32x32x16_bf16(av0, bfrag, acc0, 0, 0, 0);
            acc1 = __builtin_amdgcn_mfma_f32_32x32x16_bf16(av1, bfrag, acc1, 0, 0, 0);
        }
    }
    __syncthreads();   // all waves done reading xt -> safe to reuse as out tile

    // Epilogue: (bias+mb) + fast elu -> LDS bf16 -> coalesced uint4 stores.
    // C/D map: col=lane&31, row=(reg&3)+8*(reg>>2)+4*(lane>>5).
    const float bias = bf2f(bs[col]) + mbv;
    #pragma unroll
    for (int mt = 0; mt < 2; ++mt) {
        const floatx16 A = mt ? acc1 : acc0;
        #pragma unroll
        for (int r = 0; r < 16; ++r) {
            const int rowC = (r & 3) + 8 * (r >> 2) + 4 * (l >> 5);
            xt[(mt * 32 + rowC) * XSTR + col] = f2bf(elu_fast(A[r] + bias));
        }
    }
    __syncthreads();
    ushort_t* dst = yb + (size_t)(r0 * SGRID) * FD;
    #pragma unroll
    for (int jj = 0; jj < 4; ++jj) {
        const int e8 = (t + 256 * jj) * 8;
        const int cc = e8 >> 7, k = e8 & 127;
        *(uint4*)(dst + e8) = *(const uint4*)&xt[cc * XSTR + k];
    }
}

// ---------------------------------------------------------------------------
// Head: gather + 6-layer MLP + mask. 128 blocks (XCD-swizzled, 1 batch each)
// x 1024 threads = 16 waves doing a 16-way K-split; partials reduced via
// part[16][512] in LDS. LDS ~39 KB.
// ---------------------------------------------------------------------------
__global__ __launch_bounds__(1024) void head_kernel(
    const ushort_t* __restrict__ x,       // bf16, B x 1025 x 128
    const int* __restrict__ pos,
    const int* __restrict__ amask,
    const ushort_t* __restrict__ Wd1, const ushort_t* __restrict__ bd1,
    const ushort_t* __restrict__ Wd2, const ushort_t* __restrict__ bd2,
    const ushort_t* __restrict__ Wd3, const ushort_t* __restrict__ bd3,
    const ushort_t* __restrict__ Wp1, const ushort_t* __restrict__ bp1,
    const ushort_t* __restrict__ Wp2, const ushort_t* __restrict__ bp2,
    const ushort_t* __restrict__ Wp3, const ushort_t* __restrict__ bp3,
    ushort_t* __restrict__ out)           // bf16, B x 19
{
    const int t = threadIdx.x;
    const int b = (blockIdx.x & 7) * 16 + (blockIdx.x >> 3);  // batch on its XCD
    const int q = t >> 6;             // K-split sixteenth (wave id, 0..15)
    const int lane = t & 63;

    __shared__ float st[640];
    __shared__ float bufA[512];
    __shared__ float bufB[512];
    __shared__ float part[16][512];

    const int OFFR[5] = {-1, 0, 1, 0, 0};
    const int OFFC[5] = {0, -1, 0, 1, 0};

    // Gather state (reference's j=(pos+off+1)@[32,1] into 34-wide padded map).
    {
        const int pr = pos[b * 2 + 0], pc = pos[b * 2 + 1];
        for (int e = t; e < 640; e += 1024) {
            const int slot = e >> 7, k = e & 127;
            const int jj = (pr + OFFR[slot] + 1) * SGRID + (pc + OFFC[slot] + 1);
            const int qr = jj / (SGRID + 2), qc = jj % (SGRID + 2);
            float v = 0.f;
            if (qr >= 1 && qr <= SGRID && qc >= 1 && qc <= SGRID)
                v = bf2f(x[((size_t)b * NTOT + (qr - 1) * SGRID + (qc - 1)) * FD + k]);
            st[e] = v;
        }
    }
    __syncthreads();

    // ---- L1: 640 -> 512 (K/16 = 40 per wave; lane owns 8 cols) ----
    {
        float acc[8];
        #pragma unroll
        for (int p = 0; p < 8; ++p) acc[p] = 0.f;
        const int c0 = lane * 8;
        const int kb = q * 40;
        #pragma unroll 8
        for (int k = kb; k < kb + 40; ++k) {
            const float s = st[k];
            float f[8]; unpack8(*(const uint4*)(Wd1 + (size_t)k * 512 + c0), f);
            #pragma unroll
            for (int p = 0; p < 8; ++p) acc[p] += s * f[p];
        }
        #pragma unroll
        for (int p = 0; p < 8; ++p) part[q][c0 + p] = acc[p];
        __syncthreads();
        if (t < 512) {
            float a = bf2f(bd1[t]);
            #pragma unroll
            for (int p = 0; p < 16; ++p) a += part[p][t];
            bufA[t] = elu_fast(a);
        }
        __syncthreads();
    }
    // ---- L2: 512 -> 512 (K/16 = 32) ----
    {
        float acc[8];
        #pragma unroll
        for (int p = 0; p < 8; ++p) acc[p] = 0.f;
        const int c0 = lane * 8;
        const int kb = q * 32;
        #pragma unroll 8
        for (int k = kb; k < kb + 32; ++k) {
            const float s = bufA[k];
            float f[8]; unpack8(*(const uint4*)(Wd2 + (size_t)k * 512 + c0), f);
            #pragma unroll
            for (int p = 0; p < 8; ++p) acc[p] += s * f[p];
        }
        #pragma unroll
        for (int p = 0; p < 8; ++p) part[q][c0 + p] = acc[p];
        __syncthreads();
        if (t < 512) {
            float a = bf2f(bd2[t]);
            #pragma unroll
            for (int p = 0; p < 16; ++p) a += part[p][t];
            bufB[t] = elu_fast(a);
        }
        __syncthreads();
    }
    // ---- L3: 512 -> 256 (K/16 = 32; out -> st[0..255]) ----
    {
        float acc[4];
        #pragma unroll
        for (int p = 0; p < 4; ++p) acc[p] = 0.f;
        const int c0 = lane * 4;
        const int kb = q * 32;
        #pragma unroll 8
        for (int k = kb; k < kb + 32; ++k) {
            const float s = bufB[k];
            float f[4]; unpack4(*(const uint2*)(Wd3 + (size_t)k * 256 + c0), f);
            #pragma unroll
            for (int p = 0; p < 4; ++p) acc[p] += s * f[p];
        }
        #pragma unroll
        for (int p = 0; p < 4; ++p) part[q][c0 + p] = acc[p];
        __syncthreads();
        if (t < 256) {
            float a = bf2f(bd3[t]);
            #pragma unroll
            for (int p = 0; p < 16; ++p) a += part[p][t];
            st[t] = elu_fast(a);
        }
        __syncthreads();
    }
    // ---- L4: 256 -> 256 (K/16 = 16; st -> bufA) ----
    {
        float acc[4];
        #pragma unroll
        for (int p = 0; p < 4; ++p) acc[p] = 0.f;
        const int c0 = lane * 4;
        const int kb = q * 16;
        #pragma unroll 8
        for (int k = kb; k < kb + 16; ++k) {
            const float s = st[k];
            float f[4]; unpack4(*(const uint2*)(Wp1 + (size_t)k * 256 + c0), f);
            #pragma unroll
            for (int p = 0; p < 4; ++p) acc[p] += s * f[p];
        }
        #pragma unroll
        for (int p = 0; p < 4; ++p) part[q][c0 + p] = acc[p];
        __syncthreads();
        if (t < 256) {
            float a = bf2f(bp1[t]);
            #pragma unroll
            for (int p = 0; p < 16; ++p) a += part[p][t];
            bufA[t] = elu_fast(a);
        }
        __syncthreads();
    }
    // ---- L5: 256 -> 256 (bufA -> bufB) ----
    {
        float acc[4];
        #pragma unroll
        for (int p = 0; p < 4; ++p) acc[p] = 0.f;
        const int c0 = lane * 4;
        const int kb = q * 16;
        #pragma unroll 8
        for (int k = kb; k < kb + 16; ++k) {
            const float s = bufA[k];
            float f[4]; unpack4(*(const uint2*)(Wp2 + (size_t)k * 256 + c0), f);
            #pragma unroll
            for (int p = 0; p < 4; ++p) acc[p] += s * f[p];
        }
        #pragma unroll
        for (int p = 0; p < 4; ++p) part[q][c0 + p] = acc[p];
        __syncthreads();
        if (t < 256) {
            float a = bf2f(bp2[t]);
            #pragma unroll
            for (int p = 0; p < 16; ++p) a += part[p][t];
            bufB[t] = elu_fast(a);
        }
        __syncthreads();
    }
    // ---- L6: 256 -> 19 + mask, finite-clamped bf16 ----
    {
        float a = 0.f;
        const int kb = q * 16;
        if (lane < NACT) {
            #pragma unroll 8
            for (int k = kb; k < kb + 16; ++k)
                a += bufB[k] * bf2f(Wp3[(size_t)k * NACT + lane]);
            part[q][lane] = a;
        }
        __syncthreads();
        if (t < NACT) {
            float v = bf2f(bp3[t]);
            #pragma unroll
            for (int p = 0; p < 16; ++p) v += part[p][t];
            v += amask[b * NACT + t] ? 0.f : NEG_INF_F;
            v = fminf(fmaxf(v, -BF16_SAFE_F), BF16_SAFE_F);
            out[b * NACT + t] = f2bf(v);
        }
    }
}

extern "C" void kernel_launch(void* const* d_in, const int* in_sizes, int n_in,
                              void* d_out, int out_size, void* d_ws, size_t ws_size,
                              hipStream_t stream) {
    const ushort_t* gmap  = (const ushort_t*)d_in[0];
    const int*      pos   = (const int*)     d_in[1];
    const int*      amask = (const int*)     d_in[2];
    const ushort_t* Ws    = (const ushort_t*)d_in[3];
    const ushort_t* Wn    = (const ushort_t*)d_in[4];
    const ushort_t* bs    = (const ushort_t*)d_in[5];
    const ushort_t* Wd1   = (const ushort_t*)d_in[6];
    const ushort_t* bd1   = (const ushort_t*)d_in[7];
    const ushort_t* Wd2   = (const ushort_t*)d_in[8];
    const ushort_t* bd2   = (const ushort_t*)d_in[9];
    const ushort_t* Wd3   = (const ushort_t*)d_in[10];
    const ushort_t* bd3   = (const ushort_t*)d_in[11];
    const ushort_t* Wp1   = (const ushort_t*)d_in[12];
    const ushort_t* bp1   = (const ushort_t*)d_in[13];
    const ushort_t* Wp2   = (const ushort_t*)d_in[14];
    const ushort_t* bp2   = (const ushort_t*)d_in[15];
    const ushort_t* Wp3   = (const ushort_t*)d_in[16];
    const ushort_t* bp3   = (const ushort_t*)d_in[17];

    // Workspace: 2 bf16 activation buffers + 192 KB wfrag + 2 meta-bias bufs.
    ushort_t* x1 = (ushort_t*)d_ws;
    ushort_t* x2 = x1 + (size_t)BATCH * NTOT * FD;
    ushort_t* wfrag = x2 + (size_t)BATCH * NTOT * FD;
    float* mb1 = (float*)(wfrag + 3 * 2 * 4 * 8 * 64 * 8);
    float* mb2 = mb1 + BATCH * FD;

    gnn_setup_frags<<<48, 256, 0, stream>>>(Ws, Wn, wfrag);

    const int nblk = 17 * BATCH;   // 2176, XCD-swizzled inside the kernel
    gnn_layer<<<nblk, 256, 0, stream>>>(gmap, x1, wfrag,
                                        Ws, Wn, bs,
                                        mb1, mb1, Wn + FD * FD,
                                        /*meta_valid=*/0, /*write_mb=*/1, NCELL * FD);
    gnn_layer<<<nblk, 256, 0, stream>>>(x1, x2, wfrag + 32768,
                                        Ws + FD * FD, Wn + FD * FD, bs + FD,
                                        mb1, mb2, Wn + 2 * FD * FD,
                                        /*meta_valid=*/1, /*write_mb=*/1, NTOT * FD);
    gnn_layer<<<nblk, 256, 0, stream>>>(x2, x1, wfrag + 65536,
                                        Ws + 2 * FD * FD, Wn + 2 * FD * FD, bs + 2 * FD,
                                        mb2, mb2, Wn,
                                        /*meta_valid=*/1, /*write_mb=*/0, NTOT * FD);

    head_kernel<<<BATCH, 1024, 0, stream>>>(x1, pos, amask,
                                            Wd1, bd1, Wd2, bd2, Wd3, bd3,
                                            Wp1, bp1, Wp2, bp2, Wp3, bp3,
                                            (ushort_t*)d_out);
}